// Round 2
// baseline (572.962 us; speedup 1.0000x reference)
//
#include <hip/hip_runtime.h>
#include <stdint.h>

#define NDIM 512
#define CDIM 128
#define MDIM (NDIM*NDIM)   // 262144

typedef unsigned short u16;
typedef __bf16 bf16v8 __attribute__((ext_vector_type(8)));
typedef float f32x4 __attribute__((ext_vector_type(4)));
typedef short s16x4 __attribute__((ext_vector_type(4)));

union V16 { bf16v8 v; s16x4 h[2]; };

__device__ __forceinline__ u16 f2bf(float f){
  union { float f; uint32_t u; } v; v.f = f;
  uint32_t u = v.u;
  u += 0x7fffu + ((u >> 16) & 1u);   // round-to-nearest-even
  return (u16)(u >> 16);
}
__device__ __forceinline__ float bf2f(u16 x){
  union { uint32_t u; float f; } v; v.u = ((uint32_t)x) << 16; return v.f;
}
__device__ __forceinline__ float sigm(float x){ return 1.0f/(1.0f + __expf(-x)); }
__device__ __forceinline__ f32x4 mfma_bf16(bf16v8 a, bf16v8 b, f32x4 c){
  return __builtin_amdgcn_mfma_f32_16x16x32_bf16(a, b, c, 0, 0, 0);
}

// ---------------------------------------------------------------------------
// K0: pack weights transposed to bf16. wt[d][k], d in [0,768):
//   d<256: w_proj[:,d] ; d<512: w_gate[:,d-256] ; d<640: w_gate_out[:,d-512]
//   d>=640: w_out[:,d-640]
// ---------------------------------------------------------------------------
__global__ void k0_prep(const float* __restrict__ wp, const float* __restrict__ wg,
                        const float* __restrict__ wgo, const float* __restrict__ wo,
                        u16* __restrict__ wt){
  const int d = blockIdx.x, k = threadIdx.x;
  float v;
  if (d < 256)      v = wp[k*256 + d];
  else if (d < 512) v = wg[k*256 + (d-256)];
  else if (d < 640) v = wgo[k*128 + (d-512)];
  else              v = wo[k*128 + (d-640)];
  wt[d*CDIM + k] = f2bf(v);
}

// ---------------------------------------------------------------------------
// K1: per 64 rows: LN(fp32) -> x(bf16,LDS) -> MFMA x@[w_proj|w_gate]
//     pg = p*sigmoid(g)*mask -> LDS transpose -> AB[d][m] (d in [0,256), k-contig)
//     launch_bounds(256,3): keep af[4][4] resident (no LDS re-read), LDS 52.7KB
//     -> 3 blocks/CU.
// ---------------------------------------------------------------------------
__global__ __launch_bounds__(256, 3) void k1_ln_proj(
    const float* __restrict__ act, const float* __restrict__ mask,
    const float* __restrict__ lns, const float* __restrict__ lno,
    const u16* __restrict__ wt, u16* __restrict__ AB)
{
  __shared__ __align__(16) u16 xs[64][136];    // pitch 272B (16B-mult, +4-bank skew)
  __shared__ __align__(8)  u16 pgs[256][68];   // pitch 136B (8B-mult)
  __shared__ float msk[64];
  const int t = threadIdx.x;
  const int m0 = blockIdx.x * 64;

  { // Phase 1: layernorm, 4 threads per row
    const int r = t >> 2, q = t & 3;
    const float4* rp = (const float4*)(act + (size_t)(m0 + r)*CDIM + q*32);
    float4 v[8];
    #pragma unroll
    for (int i = 0; i < 8; ++i) v[i] = rp[i];
    float s = 0.f, s2 = 0.f;
    #pragma unroll
    for (int i = 0; i < 8; ++i){
      s  += v[i].x + v[i].y + v[i].z + v[i].w;
      s2 += v[i].x*v[i].x + v[i].y*v[i].y + v[i].z*v[i].z + v[i].w*v[i].w;
    }
    s += __shfl_xor(s, 1);  s2 += __shfl_xor(s2, 1);
    s += __shfl_xor(s, 2);  s2 += __shfl_xor(s2, 2);
    const float mean = s * (1.f/128.f);
    const float rstd = rsqrtf(s2 * (1.f/128.f) - mean*mean + 1e-5f);
    const float4* lsp = (const float4*)(lns + q*32);
    const float4* lop = (const float4*)(lno + q*32);
    #pragma unroll
    for (int i = 0; i < 8; ++i){
      const float4 sc = lsp[i], of = lop[i];
      s16x4 pk;
      pk.x = (short)f2bf((v[i].x - mean)*rstd*sc.x + of.x);
      pk.y = (short)f2bf((v[i].y - mean)*rstd*sc.y + of.y);
      pk.z = (short)f2bf((v[i].z - mean)*rstd*sc.z + of.z);
      pk.w = (short)f2bf((v[i].w - mean)*rstd*sc.w + of.w);
      *(s16x4*)&xs[r][q*32 + i*4] = pk;
    }
    if (t < 64) msk[t] = mask[m0 + t];
  }
  __syncthreads();

  const int w = t >> 6, L = t & 63, ln16 = L & 15, quad = L >> 4;
  // A fragments: A[m=lane&15][k=quad*8+j]
  bf16v8 af[4][4];
  #pragma unroll
  for (int rs = 0; rs < 4; ++rs)
    #pragma unroll
    for (int kk = 0; kk < 4; ++kk)
      af[rs][kk] = *(const bf16v8*)&xs[rs*16 + ln16][kk*32 + quad*8];

  const f32x4 zero4 = {0.f,0.f,0.f,0.f};
  // wave w owns d-cols [64w, 64w+64)
  #pragma unroll
  for (int pp = 0; pp < 4; ++pp){
    const int p = w*4 + pp;
    const u16* wpr = wt + (size_t)(16*p + ln16)*CDIM + quad*8;
    const u16* wgr = wpr + (size_t)256*CDIM;
    bf16v8 bp[4], bg[4];
    #pragma unroll
    for (int kk = 0; kk < 4; ++kk){
      bp[kk] = *(const bf16v8*)(wpr + kk*32);
      bg[kk] = *(const bf16v8*)(wgr + kk*32);
    }
    f32x4 aP[4] = {zero4, zero4, zero4, zero4};
    f32x4 aG[4] = {zero4, zero4, zero4, zero4};
    #pragma unroll
    for (int kk = 0; kk < 4; ++kk)
      #pragma unroll
      for (int rs = 0; rs < 4; ++rs){
        aP[rs] = mfma_bf16(af[rs][kk], bp[kk], aP[rs]);
        aG[rs] = mfma_bf16(af[rs][kk], bg[kk], aG[rs]);
      }
    #pragma unroll
    for (int rs = 0; rs < 4; ++rs){
      s16x4 pk;
      #pragma unroll
      for (int reg = 0; reg < 4; ++reg){
        const int ml = rs*16 + quad*4 + reg;          // C/D: row=quad*4+reg
        const float pg = aP[rs][reg] * sigm(aG[rs][reg]) * msk[ml];
        ((short*)&pk)[reg] = (short)f2bf(pg);
      }
      *(s16x4*)&pgs[16*p + ln16][rs*16 + quad*4] = pk; // 4 consecutive ml: b64
    }
  }
  __syncthreads();

  // AB store: channel-major, 64 contiguous m per block per channel
  #pragma unroll
  for (int p4 = 0; p4 < 4; ++p4){
    const int d = p4*64 + (t >> 2), q = t & 3;
    u16* dst = AB + (size_t)d*MDIM + m0 + q*16;
    #pragma unroll
    for (int x = 0; x < 4; ++x)
      *(s16x4*)(dst + x*4) = *(const s16x4*)&pgs[d][q*16 + x*4];
  }
}

// ---------------------------------------------------------------------------
// K2: per-channel triangle GEMM act2[c] = a[c] @ b[c]^T  (a=AB[2c], b=AB[2c+1])
//     128x128 tile, BK=64, 4 waves * (64x64, 4x4 accs). (unchanged this round)
// ---------------------------------------------------------------------------
__global__ __launch_bounds__(256) void k2_tri(const u16* __restrict__ AB,
                                              u16* __restrict__ act2)
{
  __shared__ __align__(16) u16 As[128][72];
  __shared__ __align__(16) u16 Bs[128][72];
  const int t = threadIdx.x, bid = blockIdx.x;
  const int c  = bid >> 4;
  const int i0 = ((bid >> 2) & 3) * 128;
  const int j0 = (bid & 3) * 128;
  const u16* Ag = AB + (size_t)(2*c)*MDIM;
  const u16* Bg = AB + (size_t)(2*c + 1)*MDIM;

  const int w = t >> 6, L = t & 63, ln16 = L & 15, quad = L >> 4;
  const int iw = (w & 1)*64, jw = (w >> 1)*64;
  const int r = t >> 1, h = t & 1;

  const f32x4 zero4 = {0.f,0.f,0.f,0.f};
  f32x4 acc[4][4];
  #pragma unroll
  for (int x = 0; x < 4; ++x)
    #pragma unroll
    for (int y = 0; y < 4; ++y) acc[x][y] = zero4;

  for (int k0 = 0; k0 < NDIM; k0 += 64){
    const u16* ga = Ag + (size_t)(i0 + r)*NDIM + k0 + h*32;
    const u16* gb = Bg + (size_t)(j0 + r)*NDIM + k0 + h*32;
    bf16v8 sa[4], sb[4];
    #pragma unroll
    for (int x = 0; x < 4; ++x){
      sa[x] = *(const bf16v8*)(ga + x*8);
      sb[x] = *(const bf16v8*)(gb + x*8);
    }
    __syncthreads();
    #pragma unroll
    for (int x = 0; x < 4; ++x){
      *(bf16v8*)&As[r][h*32 + x*8] = sa[x];
      *(bf16v8*)&Bs[r][h*32 + x*8] = sb[x];
    }
    __syncthreads();
    #pragma unroll
    for (int kk = 0; kk < 2; ++kk){
      bf16v8 ar[4], br[4];
      #pragma unroll
      for (int x = 0; x < 4; ++x) ar[x] = *(const bf16v8*)&As[iw + x*16 + ln16][kk*32 + quad*8];
      #pragma unroll
      for (int y = 0; y < 4; ++y) br[y] = *(const bf16v8*)&Bs[jw + y*16 + ln16][kk*32 + quad*8];
      #pragma unroll
      for (int x = 0; x < 4; ++x)
        #pragma unroll
        for (int y = 0; y < 4; ++y)
          acc[x][y] = mfma_bf16(ar[x], br[y], acc[x][y]);
    }
  }

  u16* op = act2 + (size_t)c*MDIM;
  #pragma unroll
  for (int x = 0; x < 4; ++x)
    #pragma unroll
    for (int y = 0; y < 4; ++y)
      #pragma unroll
      for (int reg = 0; reg < 4; ++reg){
        const int il = iw + x*16 + quad*4 + reg;
        const int jl = jw + y*16 + ln16;
        op[(size_t)(i0 + il)*NDIM + j0 + jl] = f2bf(acc[x][y][reg]);
      }
}

// ---------------------------------------------------------------------------
// K3: per (i, 64 j's):
//   (a) recompute row-LN of act rows -> xg (bf16, gate-GEMM A operand)
//   (b) gather act2[:,i,j] transposed, channel-LN over c -> xs2
//   (c) dual MFMA GEMM: out = (xs2 @ w_out + b_out) * sigmoid(xg @ w_gate_out
//       + b_gate_out) -- both outputs share the same C/D lane mapping, so the
//       gate multiply is a register op. d_out written exactly once.
// ---------------------------------------------------------------------------
__global__ __launch_bounds__(256, 3) void k3_out(
    const float* __restrict__ act, const u16* __restrict__ act2,
    const u16* __restrict__ wt,
    const float* __restrict__ lns, const float* __restrict__ lno,
    const float* __restrict__ cns, const float* __restrict__ cno,
    const float* __restrict__ bo, const float* __restrict__ bgo,
    float* __restrict__ out)
{
  __shared__ __align__(16) u16 xg[64][136];    // LN(act) rows
  __shared__ __align__(8)  u16 vsb[128][68];   // act2 transposed tile [c][jj]
  __shared__ __align__(16) u16 xs2[64][136];   // channel-normalized [jj][c]
  __shared__ float csh[128], coh[128];
  const int t = threadIdx.x;
  const int i  = blockIdx.x >> 3;
  const int j0 = (blockIdx.x & 7)*64;
  const size_t mbase = (size_t)i*NDIM + j0;

  if (t < 128){ csh[t] = cns[t]; coh[t] = cno[t]; }

  { // (a) row layernorm, 4 threads per row
    const int r = t >> 2, q = t & 3;
    const float4* rp = (const float4*)(act + (mbase + r)*CDIM + q*32);
    float4 v[8];
    #pragma unroll
    for (int x = 0; x < 8; ++x) v[x] = rp[x];
    float s = 0.f, s2 = 0.f;
    #pragma unroll
    for (int x = 0; x < 8; ++x){
      s  += v[x].x + v[x].y + v[x].z + v[x].w;
      s2 += v[x].x*v[x].x + v[x].y*v[x].y + v[x].z*v[x].z + v[x].w*v[x].w;
    }
    s += __shfl_xor(s, 1);  s2 += __shfl_xor(s2, 1);
    s += __shfl_xor(s, 2);  s2 += __shfl_xor(s2, 2);
    const float mean = s * (1.f/128.f);
    const float rstd = rsqrtf(s2 * (1.f/128.f) - mean*mean + 1e-5f);
    const float4* lsp = (const float4*)(lns + q*32);
    const float4* lop = (const float4*)(lno + q*32);
    #pragma unroll
    for (int x = 0; x < 8; ++x){
      const float4 sc = lsp[x], of = lop[x];
      s16x4 pk;
      pk.x = (short)f2bf((v[x].x - mean)*rstd*sc.x + of.x);
      pk.y = (short)f2bf((v[x].y - mean)*rstd*sc.y + of.y);
      pk.z = (short)f2bf((v[x].z - mean)*rstd*sc.z + of.z);
      pk.w = (short)f2bf((v[x].w - mean)*rstd*sc.w + of.w);
      *(s16x4*)&xg[r][q*32 + x*4] = pk;
    }
  }
  { // (b1) act2 transposed tile load (rows contiguous along jj)
    const int cc = t >> 1, h = t & 1;
    const u16* g = act2 + (size_t)cc*MDIM + mbase + h*32;
    #pragma unroll
    for (int x = 0; x < 4; ++x){
      V16 u; u.v = *(const bf16v8*)(g + x*8);
      *(s16x4*)&vsb[cc][h*32 + x*8]     = u.h[0];
      *(s16x4*)&vsb[cc][h*32 + x*8 + 4] = u.h[1];
    }
  }
  __syncthreads();
  { // (b2) per-jj stats over c (4 threads/jj, interleaved by q)
    const int jj = t >> 2, q = t & 3;
    float s = 0.f, s2 = 0.f;
    #pragma unroll
    for (int ci = 0; ci < 32; ++ci){
      const float v = bf2f(vsb[4*ci + q][jj]);
      s += v; s2 += v*v;
    }
    s += __shfl_xor(s,1); s2 += __shfl_xor(s2,1);
    s += __shfl_xor(s,2); s2 += __shfl_xor(s2,2);
    const float mean = s*(1.f/128.f);
    const float rstd = rsqrtf(s2*(1.f/128.f) - mean*mean + 1e-5f);
    #pragma unroll
    for (int ci = 0; ci < 32; ++ci){
      const int cc = 4*ci + q;
      const float v = bf2f(vsb[cc][jj]);
      xs2[jj][cc] = f2bf((v - mean)*rstd*csh[cc] + coh[cc]);
    }
  }
  __syncthreads();

  // (c) dual GEMM, wave w owns rows [16w, 16w+16)
  const int w = t >> 6, L = t & 63, ln16 = L & 15, quad = L >> 4;
  bf16v8 aO[4], aG[4];
  #pragma unroll
  for (int kk = 0; kk < 4; ++kk){
    aO[kk] = *(const bf16v8*)&xs2[w*16 + ln16][kk*32 + quad*8];
    aG[kk] = *(const bf16v8*)&xg [w*16 + ln16][kk*32 + quad*8];
  }
  const f32x4 zero4 = {0.f,0.f,0.f,0.f};
  #pragma unroll
  for (int n = 0; n < 8; ++n){
    const u16* wor = wt + (size_t)(640 + n*16 + ln16)*CDIM + quad*8;
    const u16* wgr = wt + (size_t)(512 + n*16 + ln16)*CDIM + quad*8;
    bf16v8 bO[4], bG[4];
    #pragma unroll
    for (int kk = 0; kk < 4; ++kk){
      bO[kk] = *(const bf16v8*)(wor + kk*32);
      bG[kk] = *(const bf16v8*)(wgr + kk*32);
    }
    f32x4 cO = zero4, cG = zero4;
    #pragma unroll
    for (int kk = 0; kk < 4; ++kk){
      cO = mfma_bf16(aO[kk], bO[kk], cO);
      cG = mfma_bf16(aG[kk], bG[kk], cG);
    }
    const int e = n*16 + ln16;
    const float biasO = bo[e], biasG = bgo[e];
    #pragma unroll
    for (int reg = 0; reg < 4; ++reg){
      const int jl = w*16 + quad*4 + reg;
      out[(mbase + jl)*(size_t)CDIM + e] = (cO[reg] + biasO) * sigm(cG[reg] + biasG);
    }
  }
}

// ---------------------------------------------------------------------------
extern "C" void kernel_launch(void* const* d_in, const int* in_sizes, int n_in,
                              void* d_out, int out_size, void* d_ws, size_t ws_size,
                              hipStream_t stream)
{
  const float* act = (const float*)d_in[0];
  const float* msk = (const float*)d_in[1];
  const float* lns = (const float*)d_in[2];
  const float* lno = (const float*)d_in[3];
  const float* wp  = (const float*)d_in[4];
  const float* wg  = (const float*)d_in[5];
  const float* cns = (const float*)d_in[6];
  const float* cno = (const float*)d_in[7];
  const float* wo  = (const float*)d_in[8];
  const float* bo  = (const float*)d_in[9];
  const float* wgo = (const float*)d_in[10];
  const float* bgo = (const float*)d_in[11];
  float* out = (float*)d_out;

  // ws layout: AB (256*M bf16, 128 MiB) | ACT2 (128*M bf16, 64 MiB) | WT (768*128 bf16)
  u16* AB   = (u16*)d_ws;
  u16* ACT2 = AB + (size_t)256*MDIM;
  u16* WT   = ACT2 + (size_t)128*MDIM;

  k0_prep   <<<dim3(768),  dim3(128), 0, stream>>>(wp, wg, wgo, wo, WT);
  k1_ln_proj<<<dim3(4096), dim3(256), 0, stream>>>(act, msk, lns, lno, WT, AB);
  k2_tri    <<<dim3(2048), dim3(256), 0, stream>>>(AB, ACT2);
  k3_out    <<<dim3(4096), dim3(256), 0, stream>>>(act, ACT2, WT, lns, lno,
                                                   cns, cno, bo, bgo, out);
}